// Round 1
// baseline (666.082 us; speedup 1.0000x reference)
//
#include <hip/hip_runtime.h>
#include <hip/hip_bf16.h>

using u16   = unsigned short;
using u16x8 = __attribute__((ext_vector_type(8))) unsigned short;
using s16x8 = __attribute__((ext_vector_type(8))) short;
using f32x4 = __attribute__((ext_vector_type(4))) float;

#define KPAD 136   // padded K stride (bf16 elems): 272B rows -> 16B aligned, bank-balanced b128 reads
#define EB   64    // edges per block in edge kernel

__device__ __forceinline__ float bf2f(u16 u){
  unsigned int x = ((unsigned int)u) << 16;
  float f; __builtin_memcpy(&f, &x, 4); return f;
}
__device__ __forceinline__ u16 f2bf(float f){
  __hip_bfloat16 h = __float2bfloat16(f);
  u16 u; __builtin_memcpy(&u, &h, 2); return u;
}
__device__ __forceinline__ f32x4 mfma16(s16x8 a, s16x8 b, f32x4 c){
  return __builtin_amdgcn_mfma_f32_16x16x32_bf16(a, b, c, 0, 0, 0);
}

// ---------------------------------------------------------------------------
// P3: build bf16 hi/lo transposed weight tiles + tte rows / Wo into ws.
// BT layout: [n=256][KPAD] bf16, element [n][k] = Wcat[k][n]; n<128 -> W1 col, n>=128 -> Wr col.
// ---------------------------------------------------------------------------
__global__ __launch_bounds__(256) void prep_kernel(
    const float* __restrict__ W1, const float* __restrict__ W2,
    const float* __restrict__ Wo, const float* __restrict__ Wr,
    u16* __restrict__ BTp_hi, u16* __restrict__ BTp_lo,
    u16* __restrict__ BTc_hi, u16* __restrict__ BTc_lo,
    u16* __restrict__ W2T, float* __restrict__ params)
{
  const int tid = blockIdx.x*256 + threadIdx.x;
  const int nth = gridDim.x*256;
  for (int id = tid; id < 2*256*128; id += nth){
    const int half = id >> 15;        // 0: patient k-rows (0..127), 1: condition k-rows (128..255)
    const int rem  = id & 32767;
    const int k = rem >> 8;           // 0..127
    const int n = rem & 255;          // out col: 0..127 -> W1, 128..255 -> Wr
    const float* W = (n < 128) ? W1 : Wr;
    const float v = W[(half*128 + k)*128 + (n & 127)];
    const u16 hi = f2bf(v);
    const u16 lo = f2bf(v - bf2f(hi));
    u16* dh = half ? BTc_hi : BTp_hi;
    u16* dl = half ? BTc_lo : BTp_lo;
    dh[n*KPAD + k] = hi;
    dl[n*KPAD + k] = lo;
  }
  for (int id = tid; id < 128*128; id += nth){
    const int k = id >> 7, n = id & 127;
    W2T[n*KPAD + k] = f2bf(W2[k*128 + n]);
  }
  for (int id = tid; id < 128; id += nth){
    params[id]       = W1[256*128 + id];  // w1t (tte row)
    params[128 + id] = Wr[256*128 + id];  // wrt
    params[256 + id] = Wo[id];
  }
}

// ---------------------------------------------------------------------------
// P1/P2: out[row][0..255] = emb[row][0..127] @ Wcat (+bias), split-bf16 3-MFMA (~fp32 exact).
// Block: 4 waves, 64 rows/tile, grid.y halves N (128 cols each). Grid-stride over tiles,
// B tiles staged in LDS once per block.
// ---------------------------------------------------------------------------
__global__ __launch_bounds__(256, 2) void mm_kernel(
    const float* __restrict__ emb, int nrows, int ntiles,
    const u16* __restrict__ BT_hi, const u16* __restrict__ BT_lo,
    const float* __restrict__ b1, const float* __restrict__ br,
    const float* __restrict__ b2, int has_bias,
    u16* __restrict__ outbuf)
{
  __shared__ u16 sbhi[128*KPAD];
  __shared__ u16 sblo[128*KPAD];
  const int t = threadIdx.x;
  const int ny = blockIdx.y;
  {
    const u16x8* gh = (const u16x8*)(BT_hi + ny*128*KPAD);
    const u16x8* gl = (const u16x8*)(BT_lo + ny*128*KPAD);
    u16x8* sh = (u16x8*)sbhi;
    u16x8* sl = (u16x8*)sblo;
    for (int i = t; i < 128*KPAD/8; i += 256){ sh[i] = gh[i]; sl[i] = gl[i]; }
  }
  __syncthreads();
  const int l = t & 63, w = t >> 6;
  const int lrow = l & 15, lk = l >> 4;
  for (int tile = blockIdx.x; tile < ntiles; tile += gridDim.x){
    const int row0 = tile*64 + w*16;
    const int arow = row0 + lrow;
    const float* aptr = emb + (size_t)(arow < nrows ? arow : 0) * 128;
    f32x4 acc[8];
#pragma unroll
    for (int i=0;i<8;++i) acc[i] = (f32x4){0.f,0.f,0.f,0.f};
#pragma unroll
    for (int ks = 0; ks < 4; ++ks){
      const int k0 = ks*32 + lk*8;
      const float4 x0 = *(const float4*)(aptr + k0);
      const float4 x1 = *(const float4*)(aptr + k0 + 4);
      const float xs[8] = {x0.x,x0.y,x0.z,x0.w,x1.x,x1.y,x1.z,x1.w};
      s16x8 ah, al;
#pragma unroll
      for (int q=0;q<8;++q){
        const u16 hi = f2bf(xs[q]);
        ah[q] = (short)hi;
        al[q] = (short)f2bf(xs[q] - bf2f(hi));
      }
#pragma unroll
      for (int nb = 0; nb < 8; ++nb){
        const int boff = (nb*16 + lrow)*KPAD + k0;
        const s16x8 bh = *(const s16x8*)(sbhi + boff);
        const s16x8 bl = *(const s16x8*)(sblo + boff);
        acc[nb] = mfma16(ah, bh, acc[nb]);
        acc[nb] = mfma16(al, bh, acc[nb]);
        acc[nb] = mfma16(ah, bl, acc[nb]);
      }
    }
#pragma unroll
    for (int nb=0; nb<8; ++nb){
      const int col = ny*128 + nb*16 + lrow;
      float bias = 0.f;
      if (has_bias) bias = (col < 128) ? b1[col] : (br[col-128] + b2[col-128]);
#pragma unroll
      for (int r=0; r<4; ++r){
        const int row = row0 + lk*4 + r;
        if (row < nrows) outbuf[(size_t)row*256 + col] = f2bf(acc[nb][r] + bias);
      }
    }
  }
}

// ---------------------------------------------------------------------------
// Edge kernel: 64 edges/block. Gather PP[src]/CC[dst] (bf16), assemble
// h1=relu(.+tte*w1t) and res in LDS; h1@W2 via bf16 MFMA; epilogue relu(+res)*Wo reduce.
// ---------------------------------------------------------------------------
__global__ __launch_bounds__(256, 2) void edge_kernel(
    const int* __restrict__ ei, const float* __restrict__ tte,
    const u16* __restrict__ PP, const u16* __restrict__ CC,
    const u16* __restrict__ W2T, const float* __restrict__ params,
    const float* __restrict__ bo_p, float* __restrict__ out, int E)
{
  __shared__ u16 sW2T[128*KPAD];
  __shared__ u16 sA[EB*KPAD];
  __shared__ u16 sR[EB*KPAD];
  __shared__ float sw1t[128], swrt[128], sWo[128];
  __shared__ int ssrc[EB], sdst[EB];
  __shared__ float stte[EB];
  __shared__ float souts[EB];
  const int t = threadIdx.x;
  const int e0 = blockIdx.x * EB;
  {
    const u16x8* g = (const u16x8*)W2T;
    u16x8* s = (u16x8*)sW2T;
    for (int i = t; i < 128*KPAD/8; i += 256) s[i] = g[i];
  }
  if (t < 128){ sw1t[t] = params[t]; swrt[t] = params[128+t]; sWo[t] = params[256+t]; }
  if (t < EB){
    int e = e0 + t; if (e >= E) e = E-1;
    ssrc[t] = ei[e]; sdst[t] = ei[E + e]; stte[t] = tte[e];
  }
  __syncthreads();
  // gather + layer-1 assemble: id -> (edge e, 16B chunk c); c<16 -> h1 part, c>=16 -> res part
#pragma unroll
  for (int i = 0; i < 8; ++i){
    const int id = i*256 + t;
    const int e = id >> 5, c = id & 31;
    const int s = ssrc[e], d = sdst[e];
    const float tt = stte[e];
    const u16x8 pv = *(const u16x8*)(PP + (size_t)s*256 + c*8);
    const u16x8 cv = *(const u16x8*)(CC + (size_t)d*256 + c*8);
    const int jj = (c & 15)*8;
    const float* wt = (c < 16) ? sw1t : swrt;
    u16x8 o;
#pragma unroll
    for (int q=0;q<8;++q){
      float v = bf2f(pv[q]) + bf2f(cv[q]) + tt * wt[jj+q];
      if (c < 16) v = fmaxf(v, 0.f);
      o[q] = f2bf(v);
    }
    u16* dst = (c < 16) ? (sA + e*KPAD + jj) : (sR + e*KPAD + jj);
    *(u16x8*)dst = o;
  }
  __syncthreads();
  // MFMA: wave w -> rows rh*32..+31, cols ch*64..+63
  const int l = t & 63, w = t >> 6;
  const int lrow = l & 15, lk = l >> 4;
  const int rh = w >> 1, ch = w & 1;
  f32x4 acc[2][4];
#pragma unroll
  for (int mb=0;mb<2;++mb)
#pragma unroll
    for (int nb=0;nb<4;++nb) acc[mb][nb] = (f32x4){0.f,0.f,0.f,0.f};
#pragma unroll
  for (int ks=0; ks<4; ++ks){
    const int koff = ks*32 + lk*8;
    const s16x8 a0 = *(const s16x8*)(sA + (rh*32 + lrow)*KPAD + koff);
    const s16x8 a1 = *(const s16x8*)(sA + (rh*32 + 16 + lrow)*KPAD + koff);
#pragma unroll
    for (int nb=0; nb<4; ++nb){
      const s16x8 b = *(const s16x8*)(sW2T + (ch*64 + nb*16 + lrow)*KPAD + koff);
      acc[0][nb] = mfma16(a0, b, acc[0][nb]);
      acc[1][nb] = mfma16(a1, b, acc[1][nb]);
    }
  }
  // epilogue: h2 = relu(acc + res); partial = sum_col h2*Wo[col]
  float p[2][4] = {{0.f,0.f,0.f,0.f},{0.f,0.f,0.f,0.f}};
#pragma unroll
  for (int nb=0;nb<4;++nb){
    const int col = ch*64 + nb*16 + lrow;
    const float wo = sWo[col];
#pragma unroll
    for (int mb=0;mb<2;++mb){
#pragma unroll
      for (int r=0;r<4;++r){
        const int row = rh*32 + mb*16 + lk*4 + r;
        float h2 = acc[mb][nb][r] + bf2f(sR[row*KPAD + col]);
        h2 = fmaxf(h2, 0.f);
        p[mb][r] += h2 * wo;
      }
    }
  }
#pragma unroll
  for (int off = 1; off < 16; off <<= 1){
#pragma unroll
    for (int mb=0;mb<2;++mb)
#pragma unroll
      for (int r=0;r<4;++r)
        p[mb][r] += __shfl_xor(p[mb][r], off, 64);
  }
  if (ch == 0 && lrow == 0){
#pragma unroll
    for (int mb=0;mb<2;++mb)
#pragma unroll
      for (int r=0;r<4;++r)
        souts[rh*32 + mb*16 + lk*4 + r] = p[mb][r];
  }
  __syncthreads();
  if (ch == 1 && lrow == 0){
    const float bo = bo_p[0];
#pragma unroll
    for (int mb=0;mb<2;++mb)
#pragma unroll
      for (int r=0;r<4;++r){
        const int row = rh*32 + mb*16 + lk*4 + r;
        if (e0 + row < E) out[e0 + row] = souts[row] + p[mb][r] + bo;
      }
  }
}

// ---------------------------------------------------------------------------
// Fallback (ws too small): pure fp32, 1 wave/edge. Slow but exact.
// ---------------------------------------------------------------------------
__global__ __launch_bounds__(256) void fallback_kernel(
    const float* __restrict__ pe, const float* __restrict__ ce,
    const int* __restrict__ ei, const float* __restrict__ tte,
    const float* __restrict__ W1, const float* __restrict__ b1,
    const float* __restrict__ W2, const float* __restrict__ b2,
    const float* __restrict__ Wo, const float* __restrict__ bo,
    const float* __restrict__ Wr, const float* __restrict__ br,
    float* __restrict__ out, int E)
{
  __shared__ float sh1[4][128];
  const int w = threadIdx.x >> 6, l = threadIdx.x & 63;
  const int e_raw = blockIdx.x*4 + w;
  const int e = e_raw < E ? e_raw : E-1;
  const int s = ei[e], d = ei[E + e];
  const float tt = tte[e];
  const float* xs = pe + (size_t)s*128;
  const float* xd = ce + (size_t)d*128;
  const float x0 = xs[l], x1 = xs[64+l], x2 = xd[l], x3 = xd[64+l];
  float h1a = b1[l], h1b = b1[64+l];
  float ra = br[l], rb = br[64+l];
  for (int k = 0; k < 256; ++k){
    const float xv = (k < 64) ? x0 : (k < 128) ? x1 : (k < 192) ? x2 : x3;
    const float xk = __shfl(xv, k & 63, 64);
    h1a += xk * W1[k*128 + l];
    h1b += xk * W1[k*128 + 64 + l];
    ra  += xk * Wr[k*128 + l];
    rb  += xk * Wr[k*128 + 64 + l];
  }
  h1a += tt * W1[256*128 + l];  h1b += tt * W1[256*128 + 64 + l];
  ra  += tt * Wr[256*128 + l];  rb  += tt * Wr[256*128 + 64 + l];
  sh1[w][l] = fmaxf(h1a, 0.f);
  sh1[w][64+l] = fmaxf(h1b, 0.f);
  __syncthreads();
  float h2a = b2[l] + ra, h2b = b2[64+l] + rb;
  for (int k = 0; k < 128; ++k){
    const float hk = sh1[w][k];
    h2a += hk * W2[k*128 + l];
    h2b += hk * W2[k*128 + 64 + l];
  }
  float sum = fmaxf(h2a,0.f)*Wo[l] + fmaxf(h2b,0.f)*Wo[64+l];
  for (int off = 1; off < 64; off <<= 1) sum += __shfl_xor(sum, off, 64);
  if (l == 0 && e_raw < E) out[e_raw] = sum + bo[0];
}

extern "C" void kernel_launch(void* const* d_in, const int* in_sizes, int n_in,
                              void* d_out, int out_size, void* d_ws, size_t ws_size,
                              hipStream_t stream)
{
  const float* pe  = (const float*)d_in[0];
  const float* ce  = (const float*)d_in[1];
  const int*   ei  = (const int*)d_in[2];
  const float* tte = (const float*)d_in[3];
  const float* W1  = (const float*)d_in[4];
  const float* b1  = (const float*)d_in[5];
  const float* W2  = (const float*)d_in[6];
  const float* b2  = (const float*)d_in[7];
  const float* Wo  = (const float*)d_in[8];
  const float* bo  = (const float*)d_in[9];
  const float* Wr  = (const float*)d_in[10];
  const float* br  = (const float*)d_in[11];
  float* out = (float*)d_out;
  const int E = in_sizes[3];
  const int npat  = in_sizes[0] / 128;
  const int ncond = in_sizes[1] / 128;

  char* ws = (char*)d_ws;
  const size_t sz_PP  = (size_t)npat  * 256 * 2;
  const size_t sz_CC  = (size_t)ncond * 256 * 2;
  const size_t sz_BT  = (size_t)256 * KPAD * 2;
  const size_t sz_W2T = (size_t)128 * KPAD * 2;
  const size_t off_PP = 0;
  const size_t off_CC = off_PP + sz_PP;
  const size_t off_BT = off_CC + sz_CC;
  const size_t off_W2T = off_BT + 4*sz_BT;
  const size_t off_params = off_W2T + sz_W2T;
  const size_t ws_needed = off_params + 3*128*4;

  if (ws_size >= ws_needed){
    u16* PP     = (u16*)(ws + off_PP);
    u16* CCb    = (u16*)(ws + off_CC);
    u16* BTp_hi = (u16*)(ws + off_BT);
    u16* BTp_lo = (u16*)(ws + off_BT + sz_BT);
    u16* BTc_hi = (u16*)(ws + off_BT + 2*sz_BT);
    u16* BTc_lo = (u16*)(ws + off_BT + 3*sz_BT);
    u16* W2T    = (u16*)(ws + off_W2T);
    float* params = (float*)(ws + off_params);
    prep_kernel<<<64, 256, 0, stream>>>(W1, W2, Wo, Wr, BTp_hi, BTp_lo, BTc_hi, BTc_lo, W2T, params);
    const int ptiles = (npat + 63)/64;
    mm_kernel<<<dim3(256, 2), 256, 0, stream>>>(pe, npat, ptiles, BTp_hi, BTp_lo, b1, br, b2, 0, PP);
    const int ctiles = (ncond + 63)/64;
    mm_kernel<<<dim3((unsigned)ctiles, 2), 256, 0, stream>>>(ce, ncond, ctiles, BTc_hi, BTc_lo, b1, br, b2, 1, CCb);
    edge_kernel<<<(E + EB - 1)/EB, 256, 0, stream>>>(ei, tte, PP, CCb, W2T, params, bo, out, E);
  } else {
    fallback_kernel<<<(E + 3)/4, 256, 0, stream>>>(pe, ce, ei, tte, W1, b1, W2, b2, Wo, bo, Wr, br, out, E);
  }
}